// Round 1
// baseline (158.837 us; speedup 1.0000x reference)
//
#include <hip/hip_runtime.h>

// GMMSampler: z[b,s,d] = sum_c w[b,s,c] * (mu[b,c,d] + std[b,c,d]*eps[b,s,c,d])
// w = softmax(log(alpha[b,c]) + gumbel[b,s,c])  (tau = 1.0)
// Shapes: B=32, S=128, C=64, D=512. All f32.
// Memory-bound on eps (537 MB). One block per (b,s); 256 threads; float2/lane.

#define NB 32
#define NS 128
#define NC 64
#define ND 512

__global__ __launch_bounds__(256) void gmm_sampler_kernel(
    const float* __restrict__ alpha,   // [B,C]
    const float* __restrict__ mu,      // [B,C,D]
    const float* __restrict__ stdv,    // [B,C,D]
    const float* __restrict__ gumbel,  // [B,S,C]
    const float* __restrict__ eps,     // [B,S,C,D]
    float* __restrict__ out)           // [B,S,D]
{
    const int bs  = blockIdx.x;        // 0 .. B*S-1
    const int b   = bs >> 7;           // / NS (NS=128)
    const int tid = threadIdx.x;

    __shared__ float w[NC];

    // ---- softmax over C=64 components, done by wave 0 (64 lanes) ----
    if (tid < 64) {
        const int c = tid;
        float x = logf(alpha[b * NC + c]) + gumbel[(size_t)bs * NC + c];
        // butterfly max over the 64-lane wave
        float m = x;
        #pragma unroll
        for (int off = 32; off > 0; off >>= 1)
            m = fmaxf(m, __shfl_xor(m, off));
        float e = expf(x - m);
        float ssum = e;
        #pragma unroll
        for (int off = 32; off > 0; off >>= 1)
            ssum += __shfl_xor(ssum, off);
        w[c] = e / ssum;
    }
    __syncthreads();

    // ---- accumulate z[d0], z[d0+1] over all 64 components ----
    const int d0 = tid * 2;  // 256 threads * 2 floats = 512 = ND
    const float* mu_p  = mu   + (size_t)b  * NC * ND + d0;
    const float* st_p  = stdv + (size_t)b  * NC * ND + d0;
    const float* ep_p  = eps  + (size_t)bs * NC * ND + d0;

    float accx = 0.f, accy = 0.f;
    #pragma unroll 8
    for (int c = 0; c < NC; ++c) {
        const float wc = w[c];
        float2 m2 = *(const float2*)(mu_p + (size_t)c * ND);
        float2 s2 = *(const float2*)(st_p + (size_t)c * ND);
        float2 e2 = *(const float2*)(ep_p + (size_t)c * ND);
        accx += wc * (m2.x + s2.x * e2.x);
        accy += wc * (m2.y + s2.y * e2.y);
    }

    float2 r;
    r.x = accx;
    r.y = accy;
    *(float2*)(out + (size_t)bs * ND + d0) = r;
}

extern "C" void kernel_launch(void* const* d_in, const int* in_sizes, int n_in,
                              void* d_out, int out_size, void* d_ws, size_t ws_size,
                              hipStream_t stream) {
    const float* alpha  = (const float*)d_in[0];
    const float* mu     = (const float*)d_in[1];
    const float* stdv   = (const float*)d_in[2];
    const float* gumbel = (const float*)d_in[3];
    const float* eps    = (const float*)d_in[4];
    float* out = (float*)d_out;

    dim3 grid(NB * NS);   // 4096 blocks, one per (b,s)
    dim3 block(256);
    hipLaunchKernelGGL(gmm_sampler_kernel, grid, block, 0, stream,
                       alpha, mu, stdv, gumbel, eps, out);
}

// Round 2
// 126.584 us; speedup vs baseline: 1.2548x; 1.2548x over previous
//
#include <hip/hip_runtime.h>

// GMMSampler: z[b,s,d] = sum_c w[b,s,c] * (mu[b,c,d] + std[b,c,d]*eps[b,s,c,d])
// w = softmax(log(alpha[b,c]) + gumbel[b,s,c])  (tau = 1.0)
// Shapes: B=32, S=128, C=64, D=512. All f32. Memory-bound on eps (537 MB).
// One block = 2 adjacent samples (same b); 128 threads/sample; float4/lane.
// XCD-swizzled grid for mu/std L2 locality; nontemporal eps/out.

#define NB 32
#define NS 128
#define NC 64
#define ND 512
#define NXCD 8

typedef float v4f __attribute__((ext_vector_type(4)));

__global__ __launch_bounds__(256) void gmm_sampler_kernel(
    const float* __restrict__ alpha,   // [B,C]
    const float* __restrict__ mu,      // [B,C,D]
    const float* __restrict__ stdv,    // [B,C,D]
    const float* __restrict__ gumbel,  // [B,S,C]
    const float* __restrict__ eps,     // [B,S,C,D]
    float* __restrict__ out)           // [B,S,D]
{
    // Bijective XCD swizzle: nwg = 2048, divisible by 8.
    const int nwg = (NB * NS) / 2;           // 2048
    const int cpx = nwg / NXCD;              // 256 contiguous blocks per XCD
    int blk = blockIdx.x;
    blk = (blk % NXCD) * cpx + blk / NXCD;

    const int tid  = threadIdx.x;
    const int half = tid >> 7;               // which sample of the pair
    const int bs   = blk * 2 + half;         // pairs never straddle a b-boundary
    const int b    = bs >> 7;                // / NS

    __shared__ float w[2][NC];

    // ---- softmax over C=64: wave 0 (sample 0) and wave 2 (sample 1) ----
    if ((tid & 127) < 64) {
        const int c = tid & 63;
        float x = logf(alpha[b * NC + c]) + gumbel[(size_t)bs * NC + c];
        float m = x;
        #pragma unroll
        for (int off = 32; off > 0; off >>= 1)
            m = fmaxf(m, __shfl_xor(m, off));
        float e = expf(x - m);
        float ssum = e;
        #pragma unroll
        for (int off = 32; off > 0; off >>= 1)
            ssum += __shfl_xor(ssum, off);
        w[half][c] = e / ssum;
    }
    __syncthreads();

    // ---- accumulate 4 output elements per thread over C=64 components ----
    const int d0 = (tid & 127) * 4;          // 128 threads * 4 = 512 = ND
    const v4f* mu_p = (const v4f*)(mu   + (size_t)b  * NC * ND + d0);
    const v4f* st_p = (const v4f*)(stdv + (size_t)b  * NC * ND + d0);
    const v4f* ep_p = (const v4f*)(eps  + (size_t)bs * NC * ND + d0);
    const float* wp = w[half];

    float ax = 0.f, ay = 0.f, az = 0.f, aw = 0.f;
    #pragma unroll 4
    for (int c = 0; c < NC; ++c) {
        const float wc = wp[c];
        v4f m4 = mu_p[c * (ND / 4)];
        v4f s4 = st_p[c * (ND / 4)];
        v4f e4 = __builtin_nontemporal_load(ep_p + c * (ND / 4));
        ax += wc * (m4.x + s4.x * e4.x);
        ay += wc * (m4.y + s4.y * e4.y);
        az += wc * (m4.z + s4.z * e4.z);
        aw += wc * (m4.w + s4.w * e4.w);
    }

    v4f r;
    r.x = ax; r.y = ay; r.z = az; r.w = aw;
    __builtin_nontemporal_store(r, (v4f*)(out + (size_t)bs * ND + d0));
}

extern "C" void kernel_launch(void* const* d_in, const int* in_sizes, int n_in,
                              void* d_out, int out_size, void* d_ws, size_t ws_size,
                              hipStream_t stream) {
    const float* alpha  = (const float*)d_in[0];
    const float* mu     = (const float*)d_in[1];
    const float* stdv   = (const float*)d_in[2];
    const float* gumbel = (const float*)d_in[3];
    const float* eps    = (const float*)d_in[4];
    float* out = (float*)d_out;

    dim3 grid((NB * NS) / 2);   // 2048 blocks, one per sample pair
    dim3 block(256);
    hipLaunchKernelGGL(gmm_sampler_kernel, grid, block, 0, stream,
                       alpha, mu, stdv, gumbel, eps, out);
}

// Round 3
// 89.023 us; speedup vs baseline: 1.7842x; 1.4219x over previous
//
#include <hip/hip_runtime.h>

// GMMSampler: z[b,s,d] = sum_c w[b,s,c] * (mu[b,c,d] + std[b,c,d]*eps[b,s,c,d])
// w = softmax(log(alpha[b,c]) + gumbel[b,s,c])  (tau = 1.0)
// Shapes: B=32, S=128, C=64, D=512. All f32. Memory-bound on eps (537 MB).
// Block = 8 samples (same b), 256 threads = 2 groups x 128; each thread owns a
// float4 d-slice and accumulates 4 samples, so mu/std regs are reused 4x.
// XCD-swizzled grid; nontemporal eps loads / out stores.

#define NB 32
#define NS 128
#define NC 64
#define ND 512
#define NXCD 8
#define S_BLK 8
#define GRID ((NB * NS) / S_BLK)   // 512
#define CPX (GRID / NXCD)          // 64

typedef float v4f __attribute__((ext_vector_type(4)));

__global__ __launch_bounds__(256) void gmm_sampler_kernel(
    const float* __restrict__ alpha,   // [B,C]
    const float* __restrict__ mu,      // [B,C,D]
    const float* __restrict__ stdv,    // [B,C,D]
    const float* __restrict__ gumbel,  // [B,S,C]
    const float* __restrict__ eps,     // [B,S,C,D]
    float* __restrict__ out)           // [B,S,D]
{
    // Bijective XCD swizzle (512 % 8 == 0): XCD x gets blocks [x*64, x*64+64).
    const int bid = blockIdx.x;
    const int blk = (bid % NXCD) * CPX + bid / NXCD;

    const int bs0 = blk * S_BLK;       // first sample of this block
    const int b   = bs0 >> 7;          // / NS; 16 blocks per b, never straddles

    const int tid  = threadIdx.x;
    const int wv   = tid >> 6;         // wave 0..3
    const int lane = tid & 63;

    __shared__ float w[S_BLK][NC];

    // ---- softmax over C=64: wave wv computes samples 2wv, 2wv+1 ----
    {
        const float la = logf(alpha[b * NC + lane]);
        #pragma unroll
        for (int k = 0; k < 2; ++k) {
            const int s = 2 * wv + k;
            float x = la + gumbel[(size_t)(bs0 + s) * NC + lane];
            float m = x;
            #pragma unroll
            for (int off = 32; off > 0; off >>= 1)
                m = fmaxf(m, __shfl_xor(m, off));
            float e = expf(x - m);
            float ssum = e;
            #pragma unroll
            for (int off = 32; off > 0; off >>= 1)
                ssum += __shfl_xor(ssum, off);
            w[s][lane] = e / ssum;
        }
    }
    __syncthreads();

    // ---- each thread: 4 samples x float4 d-slice, mu/std reused 4x ----
    const int grp = tid >> 7;          // 0/1: samples [grp*4, grp*4+4)
    const int d0  = (tid & 127) * 4;   // 128 threads x 4 = 512 = ND
    const int sb  = bs0 + grp * 4;

    const v4f* mu_p = (const v4f*)(mu   + (size_t)b * NC * ND + d0);
    const v4f* st_p = (const v4f*)(stdv + (size_t)b * NC * ND + d0);
    const v4f* e0_p = (const v4f*)(eps  + (size_t)(sb + 0) * NC * ND + d0);
    const v4f* e1_p = (const v4f*)(eps  + (size_t)(sb + 1) * NC * ND + d0);
    const v4f* e2_p = (const v4f*)(eps  + (size_t)(sb + 2) * NC * ND + d0);
    const v4f* e3_p = (const v4f*)(eps  + (size_t)(sb + 3) * NC * ND + d0);
    const float* w0 = w[grp * 4 + 0];
    const float* w1 = w[grp * 4 + 1];
    const float* w2 = w[grp * 4 + 2];
    const float* w3 = w[grp * 4 + 3];

    v4f a0 = {0.f, 0.f, 0.f, 0.f};
    v4f a1 = a0, a2 = a0, a3 = a0;

    #pragma unroll 4
    for (int c = 0; c < NC; ++c) {
        const int co = c * (ND / 4);
        v4f m4 = mu_p[co];
        v4f s4 = st_p[co];
        v4f q0 = __builtin_nontemporal_load(e0_p + co);
        v4f q1 = __builtin_nontemporal_load(e1_p + co);
        v4f q2 = __builtin_nontemporal_load(e2_p + co);
        v4f q3 = __builtin_nontemporal_load(e3_p + co);
        a0 += w0[c] * (m4 + s4 * q0);
        a1 += w1[c] * (m4 + s4 * q1);
        a2 += w2[c] * (m4 + s4 * q2);
        a3 += w3[c] * (m4 + s4 * q3);
    }

    __builtin_nontemporal_store(a0, (v4f*)(out + (size_t)(sb + 0) * ND + d0));
    __builtin_nontemporal_store(a1, (v4f*)(out + (size_t)(sb + 1) * ND + d0));
    __builtin_nontemporal_store(a2, (v4f*)(out + (size_t)(sb + 2) * ND + d0));
    __builtin_nontemporal_store(a3, (v4f*)(out + (size_t)(sb + 3) * ND + d0));
}

extern "C" void kernel_launch(void* const* d_in, const int* in_sizes, int n_in,
                              void* d_out, int out_size, void* d_ws, size_t ws_size,
                              hipStream_t stream) {
    const float* alpha  = (const float*)d_in[0];
    const float* mu     = (const float*)d_in[1];
    const float* stdv   = (const float*)d_in[2];
    const float* gumbel = (const float*)d_in[3];
    const float* eps    = (const float*)d_in[4];
    float* out = (float*)d_out;

    dim3 grid(GRID);   // 512 blocks, 8 samples each
    dim3 block(256);
    hipLaunchKernelGGL(gmm_sampler_kernel, grid, block, 0, stream,
                       alpha, mu, stdv, gumbel, eps, out);
}